// Round 19
// baseline (66416.150 us; speedup 1.0000x reference)
//
#include <hip/hip_runtime.h>
#include <math.h>

#define NWG  256
#define NTHR 256
#define AGT __HIP_MEMORY_SCOPE_AGENT

// LDS float offsets
#define O_W2  0        // [16][1024]  W2 = [W_ih2 | W_hh2]
#define O_W1  16384    // [16][512]   W_hh1
#define O_U   24576    // union: hstage [8][1024] / red2 [128][68] (8704 floats)
#define O_R1  33280    // red1 [128][36] pre-folded a1 partials (4608 floats)
#define O_WX  37888    // [16][2]
#define O_B1  37920    // [16]
#define O_B2  37936    // [16]
#define O_WO  37952    // [4]
#define O_XS  37956    // [8][2]
#define O_G1  37972    // [128] layer-1 gates (pre-activated)
#define O_G2  38100    // [128] layer-2 gates (pre-activated)
#define O_C1  38228    // [32]
#define O_C2  38260    // [32]
#define LDS_FLOATS 38292   // 153,168 B <= 160 KiB (still 1 WG/CU)

union U64F2 { unsigned long long u; float f[2]; };

__global__ void ws_init_kernel(unsigned* flags, float* h1g, float* h2g,
                               float* out, const float* bout, int n_out) {
    int i = blockIdx.x * blockDim.x + threadIdx.x;
    int n = gridDim.x * blockDim.x;
    float bo = bout[0];
    for (int j = i; j < 512; j += n) flags[j] = 0u;    // flagsB[256] + flagsA[256]
    for (int j = i; j < 16384; j += n) { h1g[j] = 0.0f; h2g[j] = 0.0f; }
    for (int j = i; j < n_out; j += n) out[j] = bo;    // duty atomicAdds onto b_out
}

__device__ __forceinline__ float sigm(float x) { return 1.0f / (1.0f + __expf(-x)); }
__device__ __forceinline__ float tanh_fast(float x) { return 2.0f / (1.0f + __expf(-2.0f * x)) - 1.0f; }

// Half-split fence-free barrier, s_sleep(1) backoff (R16-validated best;
// R18 proved busy-spin regresses).
__device__ __forceinline__ void gbar(unsigned* flags, int wg, int tid, unsigned ph) {
    __syncthreads();
    asm volatile("s_waitcnt vmcnt(0)" ::: "memory");
    const int half = wg & 1;
    if (tid == 0)
        __hip_atomic_store(&flags[(half << 7) + (wg >> 1)], ph, __ATOMIC_RELAXED, AGT);
    if (tid < 32) {
        const unsigned long long* f64 = (const unsigned long long*)flags + (half << 6);
        bool done;
        do {
            unsigned long long v0 = __hip_atomic_load(&f64[2 * tid],     __ATOMIC_RELAXED, AGT);
            unsigned long long v1 = __hip_atomic_load(&f64[2 * tid + 1], __ATOMIC_RELAXED, AGT);
            done = ((unsigned)v0 >= ph) && ((unsigned)(v0 >> 32) >= ph) &&
                   ((unsigned)v1 >= ph) && ((unsigned)(v1 >> 32) >= ph);
            if (!__all(done)) __builtin_amdgcn_s_sleep(1);
        } while (!__all(done));
    }
    __syncthreads();
}

// 8x coalesced coherent float4 loads WITH internal wait (R14-validated)
#define STAGE8(srcb, r0,r1,r2,r3,r4,r5,r6,r7)                            \
    asm volatile(                                                         \
        "global_load_dwordx4 %0, %8, off sc0 sc1\n\t"                     \
        "global_load_dwordx4 %1, %9, off sc0 sc1\n\t"                     \
        "global_load_dwordx4 %2, %10, off sc0 sc1\n\t"                    \
        "global_load_dwordx4 %3, %11, off sc0 sc1\n\t"                    \
        "global_load_dwordx4 %4, %12, off sc0 sc1\n\t"                    \
        "global_load_dwordx4 %5, %13, off sc0 sc1\n\t"                    \
        "global_load_dwordx4 %6, %14, off sc0 sc1\n\t"                    \
        "global_load_dwordx4 %7, %15, off sc0 sc1\n\t"                    \
        "s_waitcnt vmcnt(0)"                                              \
        : "=&v"(r0), "=&v"(r1), "=&v"(r2), "=&v"(r3),                     \
          "=&v"(r4), "=&v"(r5), "=&v"(r6), "=&v"(r7)                      \
        : "v"(srcb),        "v"(srcb + 512),  "v"(srcb + 1024),           \
          "v"(srcb + 1536), "v"(srcb + 2048), "v"(srcb + 2560),           \
          "v"(srcb + 3072), "v"(srcb + 3584)                              \
        : "memory")

__global__ __launch_bounds__(NTHR, 1) void lstm_kernel(
    const float* __restrict__ xin,  const float* __restrict__ Wih1,
    const float* __restrict__ Whh1, const float* __restrict__ bih1,
    const float* __restrict__ bhh1, const float* __restrict__ Wih2,
    const float* __restrict__ Whh2, const float* __restrict__ bih2,
    const float* __restrict__ bhh2, const float* __restrict__ Wout,
    const float* __restrict__ bout, float* __restrict__ out,
    unsigned* __restrict__ flags, float* __restrict__ h1g,
    float* __restrict__ h2g, float* __restrict__ outred, int T)
{
    __shared__ float lds[LDS_FLOATS];
    const int tid = threadIdx.x;
    const int wg  = blockIdx.x;
    const int bh  = wg & 1;         // batch half
    const int jg  = wg >> 1;        // hidden-j group
    const int j0  = jg * 4;
    const int bd  = bh * 8 + (jg & 7);  // duty batch (same half)
    const int jh  = jg >> 3;            // duty jg-octet
    unsigned* flagsA = flags + 256;     // early h1-ready flags

    // ---- one-time: load weight slice into LDS ----
    for (int idx = tid; idx < 2048; idx += NTHR) {
        int r = idx >> 7, c4 = idx & 127;
        int grow = (r >> 2) * 512 + j0 + (r & 3);
        *(float4*)&lds[O_W1 + r * 512 + c4 * 4] = *(const float4*)&Whh1[grow * 512 + c4 * 4];
    }
    for (int idx = tid; idx < 4096; idx += NTHR) {
        int r = idx >> 8, c4 = idx & 255;
        int grow = (r >> 2) * 512 + j0 + (r & 3);
        int k = c4 * 4;
        const float* src = (k < 512) ? &Wih2[grow * 512 + k] : &Whh2[grow * 512 + (k - 512)];
        *(float4*)&lds[O_W2 + r * 1024 + k] = *(const float4*)src;
    }
    if (tid < 32) {
        int r = tid >> 1, grow = (r >> 2) * 512 + j0 + (r & 3);
        lds[O_WX + tid] = Wih1[grow * 2 + (tid & 1)];
    }
    if (tid < 16) {
        int grow = (tid >> 2) * 512 + j0 + (tid & 3);
        lds[O_B1 + tid] = bih1[grow] + bhh1[grow];
        lds[O_B2 + tid] = bih2[grow] + bhh2[grow];
    }
    if (tid < 4) lds[O_WO + tid] = Wout[j0 + tid];
    if (tid < 32) { lds[O_C1 + tid] = 0.0f; lds[O_C2 + tid] = 0.0f; }

    // ---- pre-loop: fill U-h1 with h1_{-1}=0 (zeroed h1g parity 1) ----
    if (tid >= 128) {
        const float* srcb = h1g + 1 * 8192 + (bh * 8) * 512 + (tid - 128) * 4;
        float4 r0, r1, r2, r3, r4, r5, r6, r7;
        STAGE8(srcb, r0, r1, r2, r3, r4, r5, r6, r7);
        const int d = (tid - 128) * 4;
        *(float4*)&lds[O_U + 0 * 1024 + d] = r0;
        *(float4*)&lds[O_U + 1 * 1024 + d] = r1;
        *(float4*)&lds[O_U + 2 * 1024 + d] = r2;
        *(float4*)&lds[O_U + 3 * 1024 + d] = r3;
        *(float4*)&lds[O_U + 4 * 1024 + d] = r4;
        *(float4*)&lds[O_U + 5 * 1024 + d] = r5;
        *(float4*)&lds[O_U + 6 * 1024 + d] = r6;
        *(float4*)&lds[O_U + 7 * 1024 + d] = r7;
    }
    __syncthreads();

    const int wv = tid >> 6;        // wave -> gate index
    const int ks = tid & 63;        // K-split lane

    // h2-staging map: idx = i*256+tid -> b = idx>>7, c = idx&127; src off = idx*4
    const int sd0 = ((0 * 256 + tid) >> 7) * 1024 + 512 + ((0 * 256 + tid) & 127) * 4;
    const int sd1 = ((1 * 256 + tid) >> 7) * 1024 + 512 + ((1 * 256 + tid) & 127) * 4;
    const int sd2 = ((2 * 256 + tid) >> 7) * 1024 + 512 + ((2 * 256 + tid) & 127) * 4;
    const int sd3 = ((3 * 256 + tid) >> 7) * 1024 + 512 + ((3 * 256 + tid) & 127) * 4;

    unsigned ph = 0;
    float xreg = 0.0f;
    if (tid < 16 && T > 0) {
        int b = tid >> 1, cm = tid & 1;
        xreg = xin[((bh * 8 + b) * (long)T + 0) * 2 + cm];
    }

    for (int s = 0; s <= T; ++s) {
        const int p = s & 1, pq = p ^ 1;

        // ---- out duty ----
        if (s >= 2 && tid == 0) {
            const unsigned long long* row64 =
                (const unsigned long long*)(outred + pq * 2048 + bd * 128 + jh * 8);
            U64F2 v0; v0.u = __hip_atomic_load(&row64[0], __ATOMIC_RELAXED, AGT);
            U64F2 v1; v1.u = __hip_atomic_load(&row64[1], __ATOMIC_RELAXED, AGT);
            U64F2 v2; v2.u = __hip_atomic_load(&row64[2], __ATOMIC_RELAXED, AGT);
            U64F2 v3; v3.u = __hip_atomic_load(&row64[3], __ATOMIC_RELAXED, AGT);
            float sum = (v0.f[0] + v0.f[1]) + (v1.f[0] + v1.f[1])
                      + (v2.f[0] + v2.f[1]) + (v3.f[0] + v3.f[1]);
            atomicAdd(&out[bd * T + (s - 2)], sum);
        }

        // ---- XS + next xin prefetch ----
        if (tid < 16) {
            if (s < T) lds[O_XS + tid] = xreg;
            if (s + 1 < T) {
                int b = tid >> 1, cm = tid & 1;
                xreg = xin[((bh * 8 + b) * (long)T + (s + 1)) * 2 + cm];
            }
        }

        // ---- ISSUE h2_{s-2} loads (no wait; hidden under a1 GEMM) ----
        float4 s0v, s1v, s2v, s3v;
        {
            const float* h2b = h2g + pq * 8192 + (bh * 8) * 512;
            asm volatile(
                "global_load_dwordx4 %0, %4, off sc0 sc1\n\t"
                "global_load_dwordx4 %1, %5, off sc0 sc1\n\t"
                "global_load_dwordx4 %2, %6, off sc0 sc1\n\t"
                "global_load_dwordx4 %3, %7, off sc0 sc1"
                : "=&v"(s0v), "=&v"(s1v), "=&v"(s2v), "=&v"(s3v)
                : "v"(h2b + (0 * 256 + tid) * 4), "v"(h2b + (1 * 256 + tid) * 4),
                  "v"(h2b + (2 * 256 + tid) * 4), "v"(h2b + (3 * 256 + tid) * 4)
                : "memory");
        }

        // ---- a1 GEMM on prestaged h1 (no sync, no stage wait) ----
        float a1[4][8];
        #pragma unroll
        for (int r = 0; r < 4; ++r)
            #pragma unroll
            for (int b = 0; b < 8; ++b) a1[r][b] = 0.0f;
        {
            const float* W1b = &lds[O_W1 + wv * 2048];
            #pragma unroll
            for (int c = 0; c < 2; ++c) {
                const int k = ks * 4 + c * 256;
                float4 w0 = *(const float4*)&W1b[k];
                float4 w1 = *(const float4*)&W1b[512 + k];
                float4 w2 = *(const float4*)&W1b[1024 + k];
                float4 w3 = *(const float4*)&W1b[1536 + k];
                #pragma unroll
                for (int b = 0; b < 8; ++b) {
                    float4 h = *(const float4*)&lds[O_U + b * 1024 + k];
                    a1[0][b] = fmaf(w0.x,h.x,fmaf(w0.y,h.y,fmaf(w0.z,h.z,fmaf(w0.w,h.w,a1[0][b]))));
                    a1[1][b] = fmaf(w1.x,h.x,fmaf(w1.y,h.y,fmaf(w1.z,h.z,fmaf(w1.w,h.w,a1[1][b]))));
                    a1[2][b] = fmaf(w2.x,h.x,fmaf(w2.y,h.y,fmaf(w2.z,h.z,fmaf(w2.w,h.w,a1[2][b]))));
                    a1[3][b] = fmaf(w3.x,h.x,fmaf(w3.y,h.y,fmaf(w3.z,h.z,fmaf(w3.w,h.w,a1[3][b]))));
                }
            }
        }
        // pre-fold a1 k-pairs -> R1 (stride 36); ks<32 lanes write
        #pragma unroll
        for (int r = 0; r < 4; ++r)
            #pragma unroll
            for (int b = 0; b < 8; ++b) {
                float v = a1[r][b] + __shfl_xor(a1[r][b], 32);
                if (ks < 32)
                    lds[O_R1 + ((wv * 4 + r) * 8 + b) * 36 + ks] = v;
            }

        // ---- WAIT h2 loads, write to U[512..] ----
        asm volatile("s_waitcnt vmcnt(0)" ::: "memory");
        *(float4*)&lds[O_U + sd0] = s0v;
        *(float4*)&lds[O_U + sd1] = s1v;
        *(float4*)&lds[O_U + sd2] = s2v;
        *(float4*)&lds[O_U + sd3] = s3v;
        __syncthreads();   // S1: R1 + h2 staged

        // ---- G1 reduce from R1 + pre-activation ----
        {
            int o = tid >> 1, hf = tid & 1;
            const float* rr = &lds[O_R1 + o * 36 + hf * 16];
            float sum = 0.0f;
            #pragma unroll
            for (int c = 0; c < 4; ++c) { float4 v = *(const float4*)&rr[c * 4]; sum += v.x + v.y + v.z + v.w; }
            sum += __shfl_xor(sum, 1);
            if (hf == 0) {
                int r = o >> 3, b = o & 7;
                float g = sum + lds[O_B1 + r]
                        + lds[O_WX + r * 2]     * lds[O_XS + b * 2]
                        + lds[O_WX + r * 2 + 1] * lds[O_XS + b * 2 + 1];
                lds[O_G1 + o] = (wv == 2) ? tanh_fast(g) : sigm(g);
            }
        }
        __syncthreads();   // S2: G1 ready

        // ---- EARLY L1 cell update + publish h1 + flagA (before a2 GEMM!) ----
        if (tid < 32 && s < T) {
            int jj = tid >> 3, b = tid & 7;
            float gi = lds[O_G1 + (0 * 4 + jj) * 8 + b];
            float gf = lds[O_G1 + (1 * 4 + jj) * 8 + b];
            float gg = lds[O_G1 + (2 * 4 + jj) * 8 + b];
            float go = lds[O_G1 + (3 * 4 + jj) * 8 + b];
            float c  = gf * lds[O_C1 + tid] + gi * gg;
            lds[O_C1 + tid] = c;
            __hip_atomic_store(&h1g[p * 8192 + (bh * 8 + b) * 512 + j0 + jj],
                               go * tanh_fast(c), __ATOMIC_RELAXED, AGT);
        }
        if (tid < 64 && s < T) {
            asm volatile("s_waitcnt vmcnt(0)" ::: "memory");   // wave-0 h1 drain
            if (tid == 0)
                __hip_atomic_store(&flagsA[((wg & 1) << 7) + (wg >> 1)],
                                   (unsigned)(s + 1), __ATOMIC_RELAXED, AGT);
        }

        // ---- a2 GEMM full K=1024 ----
        float a2[4][8];
        #pragma unroll
        for (int r = 0; r < 4; ++r)
            #pragma unroll
            for (int b = 0; b < 8; ++b) a2[r][b] = 0.0f;
        {
            const float* W2b = &lds[O_W2 + wv * 4096];
            #pragma unroll
            for (int c = 0; c < 4; ++c) {
                const int k = ks * 4 + c * 256;
                float4 u0 = *(const float4*)&W2b[k];
                float4 u1 = *(const float4*)&W2b[1024 + k];
                float4 u2 = *(const float4*)&W2b[2048 + k];
                float4 u3 = *(const float4*)&W2b[3072 + k];
                #pragma unroll
                for (int b = 0; b < 8; ++b) {
                    float4 h = *(const float4*)&lds[O_U + b * 1024 + k];
                    a2[0][b] = fmaf(u0.x,h.x,fmaf(u0.y,h.y,fmaf(u0.z,h.z,fmaf(u0.w,h.w,a2[0][b]))));
                    a2[1][b] = fmaf(u1.x,h.x,fmaf(u1.y,h.y,fmaf(u1.z,h.z,fmaf(u1.w,h.w,a2[1][b]))));
                    a2[2][b] = fmaf(u2.x,h.x,fmaf(u2.y,h.y,fmaf(u2.z,h.z,fmaf(u2.w,h.w,a2[2][b]))));
                    a2[3][b] = fmaf(u3.x,h.x,fmaf(u3.y,h.y,fmaf(u3.z,h.z,fmaf(u3.w,h.w,a2[3][b]))));
                }
            }
        }
        __syncthreads();   // S3: U reads done -> U becomes red2

        // ---- red2 write (stride 68, 0-conflict) ----
        #pragma unroll
        for (int r = 0; r < 4; ++r)
            #pragma unroll
            for (int b = 0; b < 8; ++b)
                lds[O_U + ((wv * 4 + r) * 8 + b) * 68 + ks] = a2[r][b];
        __syncthreads();   // S4
        {
            int o = tid >> 1, hf = tid & 1;
            const float* rr = &lds[O_U + o * 68 + hf * 32];
            float sum = 0.0f;
            #pragma unroll
            for (int c = 0; c < 8; ++c) { float4 v = *(const float4*)&rr[c * 4]; sum += v.x + v.y + v.z + v.w; }
            sum += __shfl_xor(sum, 1);
            if (hf == 0) {
                float g = sum + lds[O_B2 + (o >> 3)];
                lds[O_G2 + o] = (wv == 2) ? tanh_fast(g) : sigm(g);
            }
        }
        __syncthreads();   // S5: G2 ready, red2 reads done -> U free

        // ---- waves 0-1: L2 cell update + publish h2 + outred fold ----
        if (tid >= 32 && tid < 64 && s >= 1) {
            int t2 = tid - 32, jj = t2 >> 3, b = t2 & 7;
            float gi = lds[O_G2 + (0 * 4 + jj) * 8 + b];
            float gf = lds[O_G2 + (1 * 4 + jj) * 8 + b];
            float gg = lds[O_G2 + (2 * 4 + jj) * 8 + b];
            float go = lds[O_G2 + (3 * 4 + jj) * 8 + b];
            float c  = gf * lds[O_C2 + t2] + gi * gg;
            lds[O_C2 + t2] = c;
            float h = go * tanh_fast(c);
            __hip_atomic_store(&h2g[p * 8192 + (bh * 8 + b) * 512 + j0 + jj],
                               h, __ATOMIC_RELAXED, AGT);
            float hn = lds[O_WO + jj] * h;
            hn += __shfl_xor(hn, 8);
            hn += __shfl_xor(hn, 16);
            if (jj == 0)
                __hip_atomic_store(&outred[p * 2048 + (bh * 8 + b) * 128 + jg],
                                   hn, __ATOMIC_RELAXED, AGT);
        }

        // ---- waves 2-3: pre-barrier h1_s prestage (s_sleep(1) flagA poll) ----
        if (tid >= 128 && s < T) {
            const unsigned long long* fA64 =
                (const unsigned long long*)flagsA + ((wg & 1) << 6);
            const unsigned tgt = (unsigned)(s + 1);
            int l = tid & 63;
            bool ok;
            do {
                unsigned long long v = __hip_atomic_load(&fA64[l], __ATOMIC_RELAXED, AGT);
                ok = ((unsigned)v >= tgt) && ((unsigned)(v >> 32) >= tgt);
                if (!__all(ok)) __builtin_amdgcn_s_sleep(1);
            } while (!__all(ok));
            const float* srcb = h1g + p * 8192 + (bh * 8) * 512 + (tid - 128) * 4;
            float4 r0, r1, r2, r3, r4, r5, r6, r7;
            STAGE8(srcb, r0, r1, r2, r3, r4, r5, r6, r7);
            const int d = (tid - 128) * 4;
            *(float4*)&lds[O_U + 0 * 1024 + d] = r0;
            *(float4*)&lds[O_U + 1 * 1024 + d] = r1;
            *(float4*)&lds[O_U + 2 * 1024 + d] = r2;
            *(float4*)&lds[O_U + 3 * 1024 + d] = r3;
            *(float4*)&lds[O_U + 4 * 1024 + d] = r4;
            *(float4*)&lds[O_U + 5 * 1024 + d] = r5;
            *(float4*)&lds[O_U + 6 * 1024 + d] = r6;
            *(float4*)&lds[O_U + 7 * 1024 + d] = r7;
        }

        gbar(flags, wg, tid, ++ph);
    }

    // tail: y_{T-1} partials
    if (tid == 0) {
        const unsigned long long* row64 =
            (const unsigned long long*)(outred + (T & 1) * 2048 + bd * 128 + jh * 8);
        U64F2 v0; v0.u = __hip_atomic_load(&row64[0], __ATOMIC_RELAXED, AGT);
        U64F2 v1; v1.u = __hip_atomic_load(&row64[1], __ATOMIC_RELAXED, AGT);
        U64F2 v2; v2.u = __hip_atomic_load(&row64[2], __ATOMIC_RELAXED, AGT);
        U64F2 v3; v3.u = __hip_atomic_load(&row64[3], __ATOMIC_RELAXED, AGT);
        float sum = (v0.f[0] + v0.f[1]) + (v1.f[0] + v1.f[1])
                  + (v2.f[0] + v2.f[1]) + (v3.f[0] + v3.f[1]);
        atomicAdd(&out[bd * T + (T - 1)], sum);
    }
}

extern "C" void kernel_launch(void* const* d_in, const int* in_sizes, int n_in,
                              void* d_out, int out_size, void* d_ws, size_t ws_size,
                              hipStream_t stream) {
    const float* xin  = (const float*)d_in[0];
    const float* Wih1 = (const float*)d_in[1];
    const float* Whh1 = (const float*)d_in[2];
    const float* bih1 = (const float*)d_in[3];
    const float* bhh1 = (const float*)d_in[4];
    const float* Wih2 = (const float*)d_in[5];
    const float* Whh2 = (const float*)d_in[6];
    const float* bih2 = (const float*)d_in[7];
    const float* bhh2 = (const float*)d_in[8];
    const float* Wout = (const float*)d_in[9];
    const float* bout = (const float*)d_in[10];
    float* outp = (float*)d_out;
    int T = in_sizes[0] / 32;           // input is [16][T][2]

    unsigned* flags = (unsigned*)d_ws;                  // [B x256 | A x256]
    float* h1g    = (float*)d_ws + 4096;                // [2][16][512] (zero-init)
    float* h2g    = h1g + 16384;                        // [2][16][512] (zero-init)
    float* outredp= h2g + 16384;                        // [2][16][128]

    hipLaunchKernelGGL(ws_init_kernel, dim3(64), dim3(256), 0, stream,
                       flags, h1g, h2g, outp, bout, out_size);

    // PLAIN launch (R11/R12-validated): cooperative launch silently flakes.
    hipLaunchKernelGGL(lstm_kernel, dim3(NWG), dim3(NTHR), 0, stream,
                       xin, Wih1, Whh1, bih1, bhh1, Wih2, Whh2, bih2, bhh2,
                       Wout, bout, outp, flags, h1g, h2g, outredp, T);
}

// Round 20
// 53308.405 us; speedup vs baseline: 1.2459x; 1.2459x over previous
//
#include <hip/hip_runtime.h>
#include <math.h>

#define NWG  256
#define NTHR 256
#define AGT __HIP_MEMORY_SCOPE_AGENT

// LDS float offsets
#define O_W2  0        // [16][1024]  W2 = [W_ih2 | W_hh2] rows for this j-group
#define O_W1  16384    // [16][512]   W_hh1 rows
#define O_U   24576    // union: hstage [8][1024] / red [128][68] (8704 floats)
#define O_WX  33280    // [16][2]     W_ih1 (K=2)
#define O_B1  33312    // [16]
#define O_B2  33328    // [16]
#define O_WO  33344    // [4]
#define O_XS  33348    // [8][2]
#define O_G1  33364    // [128] layer-1 gates (pre-activated)
#define O_G2  33492    // [128] layer-2 gates (pre-activated)
#define O_C1  33620    // [32]
#define O_C2  33652    // [32]
#define LDS_FLOATS 33684

union U64F2 { unsigned long long u; float f[2]; };

__global__ void ws_init_kernel(unsigned* flags, float* h1g, float* h2g,
                               float* out, const float* bout, int n_out) {
    int i = blockIdx.x * blockDim.x + threadIdx.x;
    int n = gridDim.x * blockDim.x;
    float bo = bout[0];
    for (int j = i; j < 512; j += n) flags[j] = 0u;    // flagsB[256] + flagsA[256]
    for (int j = i; j < 16384; j += n) { h1g[j] = 0.0f; h2g[j] = 0.0f; }
    for (int j = i; j < n_out; j += n) out[j] = bo;    // duty atomicAdds onto b_out
}

__device__ __forceinline__ float sigm(float x) { return 1.0f / (1.0f + __expf(-x)); }
__device__ __forceinline__ float tanh_fast(float x) { return 2.0f / (1.0f + __expf(-2.0f * x)) - 1.0f; }

// Half-split fence-free barrier (R13-R16 validated): s_sleep(1) backoff
// (R18 proved busy-spin regresses; R5/R8 proved poll mechanics are cheap).
__device__ __forceinline__ void gbar(unsigned* flags, int wg, int tid, unsigned ph) {
    __syncthreads();
    asm volatile("s_waitcnt vmcnt(0)" ::: "memory");     // drain this wave's IC ops
    const int half = wg & 1;
    if (tid == 0)
        __hip_atomic_store(&flags[(half << 7) + (wg >> 1)], ph, __ATOMIC_RELAXED, AGT);
    if (tid < 32) {
        const unsigned long long* f64 = (const unsigned long long*)flags + (half << 6);
        bool done;
        do {
            unsigned long long v0 = __hip_atomic_load(&f64[2 * tid],     __ATOMIC_RELAXED, AGT);
            unsigned long long v1 = __hip_atomic_load(&f64[2 * tid + 1], __ATOMIC_RELAXED, AGT);
            done = ((unsigned)v0 >= ph) && ((unsigned)(v0 >> 32) >= ph) &&
                   ((unsigned)v1 >= ph) && ((unsigned)(v1 >> 32) >= ph);
            if (!__all(done)) __builtin_amdgcn_s_sleep(1);
        } while (!__all(done));
    }
    __syncthreads();
}

// 8x coalesced coherent float4 loads WITH internal wait (R14-validated:
// sc0 sc1 reads through L1/L2 to the coherence point, lane-coalesced —
// 8x fewer IC transactions than atomic u64 staging)
#define STAGE8(srcb, r0,r1,r2,r3,r4,r5,r6,r7)                            \
    asm volatile(                                                         \
        "global_load_dwordx4 %0, %8, off sc0 sc1\n\t"                     \
        "global_load_dwordx4 %1, %9, off sc0 sc1\n\t"                     \
        "global_load_dwordx4 %2, %10, off sc0 sc1\n\t"                    \
        "global_load_dwordx4 %3, %11, off sc0 sc1\n\t"                    \
        "global_load_dwordx4 %4, %12, off sc0 sc1\n\t"                    \
        "global_load_dwordx4 %5, %13, off sc0 sc1\n\t"                    \
        "global_load_dwordx4 %6, %14, off sc0 sc1\n\t"                    \
        "global_load_dwordx4 %7, %15, off sc0 sc1\n\t"                    \
        "s_waitcnt vmcnt(0)"                                              \
        : "=&v"(r0), "=&v"(r1), "=&v"(r2), "=&v"(r3),                     \
          "=&v"(r4), "=&v"(r5), "=&v"(r6), "=&v"(r7)                      \
        : "v"(srcb),        "v"(srcb + 512),  "v"(srcb + 1024),           \
          "v"(srcb + 1536), "v"(srcb + 2048), "v"(srcb + 2560),           \
          "v"(srcb + 3072), "v"(srcb + 3584)                              \
        : "memory")

__global__ __launch_bounds__(NTHR, 1) void lstm_kernel(
    const float* __restrict__ xin,  const float* __restrict__ Wih1,
    const float* __restrict__ Whh1, const float* __restrict__ bih1,
    const float* __restrict__ bhh1, const float* __restrict__ Wih2,
    const float* __restrict__ Whh2, const float* __restrict__ bih2,
    const float* __restrict__ bhh2, const float* __restrict__ Wout,
    const float* __restrict__ bout, float* __restrict__ out,
    unsigned* __restrict__ flags, float* __restrict__ h1g,
    float* __restrict__ h2g, float* __restrict__ outred, int T)
{
    __shared__ float lds[LDS_FLOATS];
    const int tid = threadIdx.x;
    const int wg  = blockIdx.x;
    const int bh  = wg & 1;         // batch half: batches bh*8 .. bh*8+7
    const int jg  = wg >> 1;        // hidden-j group
    const int j0  = jg * 4;
    const int bd  = bh * 8 + (jg & 7);  // duty batch (same half as this WG)
    const int jh  = jg >> 3;            // duty jg-octet
    unsigned* flagsA = flags + 256;     // early h1-ready flags

    // ---- one-time: load weight slice into LDS ----
    for (int idx = tid; idx < 2048; idx += NTHR) {          // W1 = W_hh1 rows
        int r = idx >> 7, c4 = idx & 127;
        int grow = (r >> 2) * 512 + j0 + (r & 3);
        *(float4*)&lds[O_W1 + r * 512 + c4 * 4] = *(const float4*)&Whh1[grow * 512 + c4 * 4];
    }
    for (int idx = tid; idx < 4096; idx += NTHR) {          // W2 = [W_ih2 | W_hh2]
        int r = idx >> 8, c4 = idx & 255;
        int grow = (r >> 2) * 512 + j0 + (r & 3);
        int k = c4 * 4;
        const float* src = (k < 512) ? &Wih2[grow * 512 + k] : &Whh2[grow * 512 + (k - 512)];
        *(float4*)&lds[O_W2 + r * 1024 + k] = *(const float4*)src;
    }
    if (tid < 32) {
        int r = tid >> 1, grow = (r >> 2) * 512 + j0 + (r & 3);
        lds[O_WX + tid] = Wih1[grow * 2 + (tid & 1)];
    }
    if (tid < 16) {
        int grow = (tid >> 2) * 512 + j0 + (tid & 3);
        lds[O_B1 + tid] = bih1[grow] + bhh1[grow];
        lds[O_B2 + tid] = bih2[grow] + bhh2[grow];
    }
    if (tid < 4) lds[O_WO + tid] = Wout[j0 + tid];
    if (tid < 32) { lds[O_C1 + tid] = 0.0f; lds[O_C2 + tid] = 0.0f; }

    // ---- pre-loop: fill U-h1 with h1_{-1}=0 (from zeroed h1g parity 1) ----
    if (tid >= 128) {
        const float* srcb = h1g + 1 * 8192 + (bh * 8) * 512 + (tid - 128) * 4;
        float4 r0, r1, r2, r3, r4, r5, r6, r7;
        STAGE8(srcb, r0, r1, r2, r3, r4, r5, r6, r7);
        const int d = (tid - 128) * 4;
        *(float4*)&lds[O_U + 0 * 1024 + d] = r0;
        *(float4*)&lds[O_U + 1 * 1024 + d] = r1;
        *(float4*)&lds[O_U + 2 * 1024 + d] = r2;
        *(float4*)&lds[O_U + 3 * 1024 + d] = r3;
        *(float4*)&lds[O_U + 4 * 1024 + d] = r4;
        *(float4*)&lds[O_U + 5 * 1024 + d] = r5;
        *(float4*)&lds[O_U + 6 * 1024 + d] = r6;
        *(float4*)&lds[O_U + 7 * 1024 + d] = r7;
    }
    __syncthreads();

    const int wv = tid >> 6;        // wave -> 4 gate rows; also == gate index in reduce
    const int ks = tid & 63;        // K-split lane
    unsigned ph = 0;

    // xin register prefetch (one superstep ahead)
    float xreg = 0.0f;
    if (tid < 16 && T > 0) {
        int b = tid >> 1, cm = tid & 1;
        xreg = xin[((bh * 8 + b) * (long)T + 0) * 2 + cm];
    }

    for (int s = 0; s <= T; ++s) {
        const int p = s & 1, pq = p ^ 1;

        // ---- out duty (atomicAdd onto b_out-prefilled out) ----
        if (s >= 2 && tid == 0) {
            const unsigned long long* row64 =
                (const unsigned long long*)(outred + pq * 2048 + bd * 128 + jh * 8);
            U64F2 v0; v0.u = __hip_atomic_load(&row64[0], __ATOMIC_RELAXED, AGT);
            U64F2 v1; v1.u = __hip_atomic_load(&row64[1], __ATOMIC_RELAXED, AGT);
            U64F2 v2; v2.u = __hip_atomic_load(&row64[2], __ATOMIC_RELAXED, AGT);
            U64F2 v3; v3.u = __hip_atomic_load(&row64[3], __ATOMIC_RELAXED, AGT);
            float sum = (v0.f[0] + v0.f[1]) + (v1.f[0] + v1.f[1])
                      + (v2.f[0] + v2.f[1]) + (v3.f[0] + v3.f[1]);
            atomicAdd(&out[bd * T + (s - 2)], sum);
        }

        // ---- XS from prefetched register; issue next-step prefetch ----
        if (tid < 16) {
            if (s < T) lds[O_XS + tid] = xreg;
            if (s + 1 < T) {
                int b = tid >> 1, cm = tid & 1;
                xreg = xin[((bh * 8 + b) * (long)T + (s + 1)) * 2 + cm];
            }
        }

        // ---- post-barrier staging: h2_{s-2} half only (waves 0-1) ----
        if (tid < 128) {
            const float* srcb = h2g + pq * 8192 + (bh * 8) * 512 + tid * 4;
            float4 r0, r1, r2, r3, r4, r5, r6, r7;
            STAGE8(srcb, r0, r1, r2, r3, r4, r5, r6, r7);
            const int d = 512 + tid * 4;
            *(float4*)&lds[O_U + 0 * 1024 + d] = r0;
            *(float4*)&lds[O_U + 1 * 1024 + d] = r1;
            *(float4*)&lds[O_U + 2 * 1024 + d] = r2;
            *(float4*)&lds[O_U + 3 * 1024 + d] = r3;
            *(float4*)&lds[O_U + 4 * 1024 + d] = r4;
            *(float4*)&lds[O_U + 5 * 1024 + d] = r5;
            *(float4*)&lds[O_U + 6 * 1024 + d] = r6;
            *(float4*)&lds[O_U + 7 * 1024 + d] = r7;
        }
        __syncthreads();

        // ---- fused gate GEMMs: L2 (K=1024) + L1 (K=512), shared h loads ----
        float a1[4][8], a2[4][8];
        #pragma unroll
        for (int r = 0; r < 4; ++r)
            #pragma unroll
            for (int b = 0; b < 8; ++b) { a1[r][b] = 0.0f; a2[r][b] = 0.0f; }
        {
            const float* W2b = &lds[O_W2 + wv * 4096];
            const float* W1b = &lds[O_W1 + wv * 2048];
            #pragma unroll
            for (int c = 0; c < 4; ++c) {
                const int k = ks * 4 + c * 256;
                float4 u0 = *(const float4*)&W2b[k];
                float4 u1 = *(const float4*)&W2b[1024 + k];
                float4 u2 = *(const float4*)&W2b[2048 + k];
                float4 u3 = *(const float4*)&W2b[3072 + k];
                float4 w0, w1, w2, w3;
                if (c < 2) {
                    w0 = *(const float4*)&W1b[k];
                    w1 = *(const float4*)&W1b[512 + k];
                    w2 = *(const float4*)&W1b[1024 + k];
                    w3 = *(const float4*)&W1b[1536 + k];
                }
                #pragma unroll
                for (int b = 0; b < 8; ++b) {
                    float4 h = *(const float4*)&lds[O_U + b * 1024 + k];
                    a2[0][b] = fmaf(u0.x,h.x,fmaf(u0.y,h.y,fmaf(u0.z,h.z,fmaf(u0.w,h.w,a2[0][b]))));
                    a2[1][b] = fmaf(u1.x,h.x,fmaf(u1.y,h.y,fmaf(u1.z,h.z,fmaf(u1.w,h.w,a2[1][b]))));
                    a2[2][b] = fmaf(u2.x,h.x,fmaf(u2.y,h.y,fmaf(u2.z,h.z,fmaf(u2.w,h.w,a2[2][b]))));
                    a2[3][b] = fmaf(u3.x,h.x,fmaf(u3.y,h.y,fmaf(u3.z,h.z,fmaf(u3.w,h.w,a2[3][b]))));
                    if (c < 2) {
                        a1[0][b] = fmaf(w0.x,h.x,fmaf(w0.y,h.y,fmaf(w0.z,h.z,fmaf(w0.w,h.w,a1[0][b]))));
                        a1[1][b] = fmaf(w1.x,h.x,fmaf(w1.y,h.y,fmaf(w1.z,h.z,fmaf(w1.w,h.w,a1[1][b]))));
                        a1[2][b] = fmaf(w2.x,h.x,fmaf(w2.y,h.y,fmaf(w2.z,h.z,fmaf(w2.w,h.w,a1[2][b]))));
                        a1[3][b] = fmaf(w3.x,h.x,fmaf(w3.y,h.y,fmaf(w3.z,h.z,fmaf(w3.w,h.w,a1[3][b]))));
                    }
                }
            }
        }
        __syncthreads();                // staged-h reads done; U becomes red[]

        // ---- reduce L1 (stride 68, 0-conflict) + pre-activation (wave-uniform) ----
        #pragma unroll
        for (int r = 0; r < 4; ++r)
            #pragma unroll
            for (int b = 0; b < 8; ++b)
                lds[O_U + ((wv * 4 + r) * 8 + b) * 68 + ks] = a1[r][b];
        __syncthreads();
        {
            int o = tid >> 1, hf = tid & 1;
            const float* rr = &lds[O_U + o * 68 + hf * 32];
            float sum = 0.0f;
            #pragma unroll
            for (int c = 0; c < 8; ++c) { float4 v = *(const float4*)&rr[c * 4]; sum += v.x + v.y + v.z + v.w; }
            sum += __shfl_xor(sum, 1);
            if (hf == 0) {
                int r = o >> 3, b = o & 7;
                float g = sum + lds[O_B1 + r]
                        + lds[O_WX + r * 2]     * lds[O_XS + b * 2]
                        + lds[O_WX + r * 2 + 1] * lds[O_XS + b * 2 + 1];
                lds[O_G1 + o] = (wv == 2) ? tanh_fast(g) : sigm(g);
            }
        }
        __syncthreads();

        // ---- EARLY L1 cell update + publish h1 ----
        if (tid < 32 && s < T) {
            int jj = tid >> 3, b = tid & 7;
            float gi = lds[O_G1 + (0 * 4 + jj) * 8 + b];
            float gf = lds[O_G1 + (1 * 4 + jj) * 8 + b];
            float gg = lds[O_G1 + (2 * 4 + jj) * 8 + b];
            float go = lds[O_G1 + (3 * 4 + jj) * 8 + b];
            float c  = gf * lds[O_C1 + tid] + gi * gg;
            lds[O_C1 + tid] = c;
            __hip_atomic_store(&h1g[p * 8192 + (bh * 8 + b) * 512 + j0 + jj],
                               go * tanh_fast(c), __ATOMIC_RELAXED, AGT);
        }

        // ---- reduce L2 + pre-activation ----
        #pragma unroll
        for (int r = 0; r < 4; ++r)
            #pragma unroll
            for (int b = 0; b < 8; ++b)
                lds[O_U + ((wv * 4 + r) * 8 + b) * 68 + ks] = a2[r][b];

        // early h1-ready flag (wave 0 drains h1 stores, raises flagsA)
        if (tid < 64 && s < T) {
            asm volatile("s_waitcnt vmcnt(0)" ::: "memory");
            if (tid == 0)
                __hip_atomic_store(&flagsA[((wg & 1) << 7) + (wg >> 1)],
                                   (unsigned)(s + 1), __ATOMIC_RELAXED, AGT);
        }
        __syncthreads();
        {
            int o = tid >> 1, hf = tid & 1;
            const float* rr = &lds[O_U + o * 68 + hf * 32];
            float sum = 0.0f;
            #pragma unroll
            for (int c = 0; c < 8; ++c) { float4 v = *(const float4*)&rr[c * 4]; sum += v.x + v.y + v.z + v.w; }
            sum += __shfl_xor(sum, 1);
            if (hf == 0) {
                float g = sum + lds[O_B2 + (o >> 3)];
                lds[O_G2 + o] = (wv == 2) ? tanh_fast(g) : sigm(g);
            }
        }
        __syncthreads();    // S6: red-a2 reads done -> U region free

        // ---- waves 0-1: L2 cell update + publish h2 + outred fold ----
        if (tid >= 32 && tid < 64 && s >= 1) {
            int t2 = tid - 32, jj = t2 >> 3, b = t2 & 7;
            float gi = lds[O_G2 + (0 * 4 + jj) * 8 + b];
            float gf = lds[O_G2 + (1 * 4 + jj) * 8 + b];
            float gg = lds[O_G2 + (2 * 4 + jj) * 8 + b];
            float go = lds[O_G2 + (3 * 4 + jj) * 8 + b];
            float c  = gf * lds[O_C2 + t2] + gi * gg;
            lds[O_C2 + t2] = c;
            float h = go * tanh_fast(c);
            __hip_atomic_store(&h2g[p * 8192 + (bh * 8 + b) * 512 + j0 + jj],
                               h, __ATOMIC_RELAXED, AGT);
            float hn = lds[O_WO + jj] * h;
            hn += __shfl_xor(hn, 8);
            hn += __shfl_xor(hn, 16);
            if (jj == 0)
                __hip_atomic_store(&outred[p * 2048 + (bh * 8 + b) * 128 + jg],
                                   hn, __ATOMIC_RELAXED, AGT);
        }

        // ---- waves 2-3: pre-barrier h1_s prestage (s_sleep(1) flagA poll) ----
        if (tid >= 128 && s < T) {
            const unsigned long long* fA64 =
                (const unsigned long long*)flagsA + ((wg & 1) << 6);
            const unsigned tgt = (unsigned)(s + 1);
            int l = tid & 63;
            bool ok;
            do {
                unsigned long long v = __hip_atomic_load(&fA64[l], __ATOMIC_RELAXED, AGT);
                ok = ((unsigned)v >= tgt) && ((unsigned)(v >> 32) >= tgt);
                if (!__all(ok)) __builtin_amdgcn_s_sleep(1);
            } while (!__all(ok));
            const float* srcb = h1g + p * 8192 + (bh * 8) * 512 + (tid - 128) * 4;
            float4 r0, r1, r2, r3, r4, r5, r6, r7;
            STAGE8(srcb, r0, r1, r2, r3, r4, r5, r6, r7);
            const int d = (tid - 128) * 4;
            *(float4*)&lds[O_U + 0 * 1024 + d] = r0;
            *(float4*)&lds[O_U + 1 * 1024 + d] = r1;
            *(float4*)&lds[O_U + 2 * 1024 + d] = r2;
            *(float4*)&lds[O_U + 3 * 1024 + d] = r3;
            *(float4*)&lds[O_U + 4 * 1024 + d] = r4;
            *(float4*)&lds[O_U + 5 * 1024 + d] = r5;
            *(float4*)&lds[O_U + 6 * 1024 + d] = r6;
            *(float4*)&lds[O_U + 7 * 1024 + d] = r7;
        }

        gbar(flags, wg, tid, ++ph);     // half-barrier, one per superstep
    }

    // tail: y_{T-1} partials
    if (tid == 0) {
        const unsigned long long* row64 =
            (const unsigned long long*)(outred + (T & 1) * 2048 + bd * 128 + jh * 8);
        U64F2 v0; v0.u = __hip_atomic_load(&row64[0], __ATOMIC_RELAXED, AGT);
        U64F2 v1; v1.u = __hip_atomic_load(&row64[1], __ATOMIC_RELAXED, AGT);
        U64F2 v2; v2.u = __hip_atomic_load(&row64[2], __ATOMIC_RELAXED, AGT);
        U64F2 v3; v3.u = __hip_atomic_load(&row64[3], __ATOMIC_RELAXED, AGT);
        float sum = (v0.f[0] + v0.f[1]) + (v1.f[0] + v1.f[1])
                  + (v2.f[0] + v2.f[1]) + (v3.f[0] + v3.f[1]);
        atomicAdd(&out[bd * T + (T - 1)], sum);
    }
}

extern "C" void kernel_launch(void* const* d_in, const int* in_sizes, int n_in,
                              void* d_out, int out_size, void* d_ws, size_t ws_size,
                              hipStream_t stream) {
    const float* xin  = (const float*)d_in[0];
    const float* Wih1 = (const float*)d_in[1];
    const float* Whh1 = (const float*)d_in[2];
    const float* bih1 = (const float*)d_in[3];
    const float* bhh1 = (const float*)d_in[4];
    const float* Wih2 = (const float*)d_in[5];
    const float* Whh2 = (const float*)d_in[6];
    const float* bih2 = (const float*)d_in[7];
    const float* bhh2 = (const float*)d_in[8];
    const float* Wout = (const float*)d_in[9];
    const float* bout = (const float*)d_in[10];
    float* outp = (float*)d_out;
    int T = in_sizes[0] / 32;           // input is [16][T][2]

    unsigned* flags = (unsigned*)d_ws;                  // [B x256 | A x256]
    float* h1g    = (float*)d_ws + 4096;                // [2][16][512] (zero-init)
    float* h2g    = h1g + 16384;                        // [2][16][512] (zero-init)
    float* outredp= h2g + 16384;                        // [2][16][128]

    hipLaunchKernelGGL(ws_init_kernel, dim3(64), dim3(256), 0, stream,
                       flags, h1g, h2g, outp, bout, out_size);

    // PLAIN launch (R11/R12-validated): cooperative launch silently flakes.
    // Co-residency is structural: 134KB LDS -> 1 block/CU, grid == 256 == CUs.
    hipLaunchKernelGGL(lstm_kernel, dim3(NWG), dim3(NTHR), 0, stream,
                       xin, Wih1, Whh1, bih1, bhh1, Wih2, Whh2, bih2, bhh2,
                       Wout, bout, outp, flags, h1g, h2g, outredp, T);
}